// Round 7
// baseline (478.505 us; speedup 1.0000x reference)
//
#include <hip/hip_runtime.h>
#include <stdint.h>

// ---------------------------------------------------------------------------
// GTU block: rmsnorm -> [u|v] GEMM+silu -> depthwise 2D circular Toeplitz conv
//            -> gate -> out = g@Wo + bo + x
// R7: (a) gemm0 widened to 128x256 tile / 512 thr (staging per output -25%);
//     (b) rpe layers 1-3 merged into one 2-block kernel (kills 2 launches +
//     drains); (c) conv_k register-prefetches next batch's V/U (T14).
// ---------------------------------------------------------------------------

typedef __attribute__((ext_vector_type(4))) float  f32x4;
typedef __attribute__((ext_vector_type(8))) short  s16x8;
typedef __attribute__((ext_vector_type(8))) unsigned short u16x8;
typedef __attribute__((ext_vector_type(4))) unsigned short u16x4;
typedef unsigned short u16;

#define M_TOT 32768      // B*H*W

__device__ __forceinline__ u16 f2bf(float f) {
  union { float f; unsigned int u; } v; v.f = f;
  unsigned int r = (v.u + 0x7FFFu + ((v.u >> 16) & 1u)) >> 16;
  return (u16)r;
}
__device__ __forceinline__ float bf2f(u16 h) {
  union { unsigned int u; float f; } v; v.u = ((unsigned int)h) << 16;
  return v.f;
}
__device__ __forceinline__ float silu_f(float x) {
  return x * __builtin_amdgcn_rcpf(1.f + __expf(-x));
}

__device__ __forceinline__ void gload_lds16(const u16* g, u16* l) {
  __builtin_amdgcn_global_load_lds(
      (const __attribute__((address_space(1))) uint32_t*)g,
      (__attribute__((address_space(3))) uint32_t*)l, 16, 0, 0);
}

// ---------------------------------------------------------------------------
// setup_k: blockIdx-partitioned fusion (rmsnorm | weight transposes | rpe-in)
// ---------------------------------------------------------------------------
__global__ __launch_bounds__(256) void setup_k(
    const float* __restrict__ x, u16* __restrict__ xn,
    const float* __restrict__ Wu, const float* __restrict__ Wv,
    const float* __restrict__ Wo, u16* __restrict__ Wuvt, u16* __restrict__ Wot,
    const float* __restrict__ r1lw, const float* __restrict__ r1ow,
    const float* __restrict__ r2lw, const float* __restrict__ r2ow,
    u16* __restrict__ lwT, u16* __restrict__ owT,
    const float* __restrict__ r1pw, const float* __restrict__ r1pb,
    const float* __restrict__ r2pw, const float* __restrict__ r2pb,
    float* __restrict__ X0) {
  __shared__ float sm[32][33];
  const int bid = blockIdx.x;
  const int tid = threadIdx.x;

  if (bid < 8192) {                     // ---- rmsnorm ----
    int row  = bid * 4 + (tid >> 6);
    int lane = tid & 63;
    const float* xr = x + (size_t)row * 384 + lane;
    float v[6]; float ss = 0.f;
#pragma unroll
    for (int i = 0; i < 6; i++) { v[i] = xr[i * 64]; ss += v[i] * v[i]; }
#pragma unroll
    for (int off = 32; off > 0; off >>= 1) ss += __shfl_xor(ss, off);
    float sc = rsqrtf(ss * (1.f / 384.f) + 1e-6f);
    u16* o = xn + (size_t)row * 384 + lane;
#pragma unroll
    for (int i = 0; i < 6; i++) o[i * 64] = f2bf(v[i] * sc);
  } else if (bid < 11360) {             // ---- tiled transposes ----
    int b = bid - 8192;
    const float* src; u16* dst; int C, DS, R0, C0;
    if (b < 2304) {
      int mlp = b / 1152, r = b % 1152;
      if (r < 768) {
        int L = r / 256, t = r % 256;
        R0 = (t / 16) * 32; C0 = (t % 16) * 32;
        src = (mlp ? r2lw : r1lw) + (size_t)L * 262144;
        dst = lwT + (size_t)(mlp * 3 + L) * 262144;
        C = 512; DS = 512;
      } else {
        int t = r - 768;
        R0 = (t / 24) * 32; C0 = (t % 24) * 32;
        src = mlp ? r2ow : r1ow;
        dst = owT + (size_t)mlp * 393216;
        C = 768; DS = 512;
      }
    } else {
      int t = b - 2304;
      if (t < 288)      { R0 = (t / 24) * 32; C0 = (t % 24) * 32;
                          src = Wu; C = 768; dst = Wuvt;             DS = 384; }
      else if (t < 576) { int t2 = t - 288; R0 = (t2 / 24) * 32; C0 = (t2 % 24) * 32;
                          src = Wv; C = 768; dst = Wuvt + 768 * 384; DS = 384; }
      else              { int t2 = t - 576; R0 = (t2 / 12) * 32; C0 = (t2 % 12) * 32;
                          src = Wo; C = 384; dst = Wot;              DS = 768; }
    }
    int lx = tid % 32, ly = tid / 32;
#pragma unroll
    for (int q = 0; q < 4; q++) {
      int y = q * 8 + ly;
      sm[y][lx] = src[(size_t)(R0 + y) * C + C0 + lx];
    }
    __syncthreads();
#pragma unroll
    for (int q = 0; q < 4; q++) {
      int y = q * 8 + ly;
      dst[(size_t)(C0 + y) * DS + R0 + lx] = f2bf(sm[lx][y]);
    }
  } else {                              // ---- rpe input layer ----
    int idx = (bid - 11360) * 256 + tid;
    int gid = idx * 4;
    int row = gid >> 9, col = gid & 511;
    int mlp = row >> 7, p = row & 127;
    float pos = (p < 64) ? (float)p : ((p == 64) ? 0.f : (float)(p - 128));
    const float* pw = (mlp ? r2pw : r1pw) + col;
    const float* pb = (mlp ? r2pb : r1pb) + col;
    f32x4 w = *(const f32x4*)pw;
    f32x4 bb = *(const f32x4*)pb;
    f32x4 o;
#pragma unroll
    for (int e = 0; e < 4; e++) o[e] = fmaxf(pos * w[e] + bb[e], 0.f);
    *(f32x4*)(X0 + gid) = o;
  }
}

// ---------------------------------------------------------------------------
// rpe_all_k: layers 1-3 fused.  grid 2 (block = mlp), 1024 thr (16 waves,
// 4m x 4n).  Per layer: sumsq -> 8 K-tiles {stage A (relu*srms->bf16, LDS
// swizzled) + B (gload_lds, pre-swizzled src), MFMA} -> +bias -> X ping-pong
// in global (intra-block visibility via __syncthreads).
// L0: X0->X1, L1: X1->X0, L2: X0->X1  (final in X1).
// ---------------------------------------------------------------------------
__global__ __launch_bounds__(1024) void rpe_all_k(
    float* __restrict__ X0, float* __restrict__ X1,
    const u16* __restrict__ lwT,
    const float* __restrict__ r1lb, const float* __restrict__ r2lb) {
  __shared__ __align__(16) u16 Bs[512 * 64];   // 64 KB
  __shared__ __align__(16) u16 As[128 * 64];   // 16 KB
  __shared__ float scale[128];

  const int tid  = threadIdx.x;
  const int mlp  = blockIdx.x;
  const int lane = tid & 63;
  const int w    = tid >> 6;           // 0..15
  const int wm   = w >> 2;             // 0..3  (m-tile of 32)
  const int wn   = w & 3;              // 0..3  (n-slice of 128)
  const int fl   = lane & 15, fh = lane >> 4;
  const float* lb = mlp ? r2lb : r1lb;

  // staging coords
  const int arow = tid >> 3, ac = tid & 7;            // A: 1 chunk/thread
  const int sqrow = tid >> 3, sqseg = tid & 7;        // sumsq: 8 thr/row

  for (int L = 0; L < 3; L++) {
    float* Xin  = (L & 1) ? X1 : X0;
    float* Xout = (L & 1) ? X0 : X1;
    const float* Xm = Xin + (size_t)mlp * 128 * 512;
    float* Xo = Xout + (size_t)mlp * 128 * 512;
    const u16* WT = lwT + (size_t)(mlp * 3 + L) * 262144;
    const float* bias = lb + L * 512;

    // ---- sumsq -> scale ----
    {
      const float* xr = Xm + (size_t)sqrow * 512 + sqseg * 64;
      float ss = 0.f;
#pragma unroll
      for (int q = 0; q < 16; q++) {
        f32x4 v = *(const f32x4*)(xr + q * 4);
        ss += v[0] * v[0] + v[1] * v[1] + v[2] * v[2] + v[3] * v[3];
      }
      ss += __shfl_xor(ss, 1);
      ss += __shfl_xor(ss, 2);
      ss += __shfl_xor(ss, 4);
      if ((tid & 7) == 0) scale[sqrow] = rsqrtf(ss * (1.f / 512.f) + 1e-6f);
    }
    __syncthreads();

    f32x4 acc[2][8];
    {
      f32x4 z = {0.f, 0.f, 0.f, 0.f};
#pragma unroll
      for (int i = 0; i < 2; i++)
#pragma unroll
        for (int j = 0; j < 8; j++) acc[i][j] = z;
    }
    const float s_ = scale[arow];

    for (int kt = 0; kt < 512; kt += 64) {
      // A: relu(x)*scale -> bf16, swizzled LDS write
      {
        const float* xp = Xm + (size_t)arow * 512 + kt + ac * 8;
        f32x4 v0 = *(const f32x4*)xp;
        f32x4 v1 = *(const f32x4*)(xp + 4);
        u16x8 pk;
#pragma unroll
        for (int e = 0; e < 4; e++) pk[e]     = f2bf(fmaxf(v0[e], 0.f) * s_);
#pragma unroll
        for (int e = 0; e < 4; e++) pk[4 + e] = f2bf(fmaxf(v1[e], 0.f) * s_);
        *(u16x8*)(&As[arow * 64 + ((ac ^ (arow & 7)) * 8)]) = pk;
      }
      // B: 4 gloads/thread, pre-swizzled source, linear LDS dest
#pragma unroll
      for (int q = 0; q < 4; q++) {
        int id = q * 1024 + tid;
        int row = id >> 3, c = id & 7;
        gload_lds16(WT + (size_t)row * 512 + kt + ((c ^ (row & 7)) * 8),
                    Bs + id * 8);
      }
      __syncthreads();
#pragma unroll
      for (int ks = 0; ks < 2; ks++) {
        const int xc = ((ks * 4 + fh) ^ (fl & 7)) * 8;
        s16x8 af0 = *(const s16x8*)(&As[(wm * 32 + fl) * 64 + xc]);
        s16x8 af1 = *(const s16x8*)(&As[(wm * 32 + 16 + fl) * 64 + xc]);
#pragma unroll
        for (int j = 0; j < 8; j++) {
          s16x8 bfr = *(const s16x8*)(&Bs[(wn * 128 + j * 16 + fl) * 64 + xc]);
          acc[0][j] = __builtin_amdgcn_mfma_f32_16x16x32_bf16(af0, bfr, acc[0][j], 0, 0, 0);
          acc[1][j] = __builtin_amdgcn_mfma_f32_16x16x32_bf16(af1, bfr, acc[1][j], 0, 0, 0);
        }
      }
      __syncthreads();
    }

    // ---- epilogue: +bias -> Xout ----
#pragma unroll
    for (int i = 0; i < 2; i++)
#pragma unroll
      for (int j = 0; j < 8; j++) {
        int c = wn * 128 + j * 16 + fl;
        float bv_ = bias[c];
#pragma unroll
        for (int q = 0; q < 4; q++) {
          int r = wm * 32 + i * 16 + fh * 4 + q;
          Xo[(size_t)r * 512 + c] = acc[i][j][q] + bv_;
        }
      }
    __syncthreads();   // Xout visible + LDS reusable before next layer
  }
}

// ---------------------------------------------------------------------------
// rpe_layer_k<768,true>: final RPE projection (N=768), out transposed (C,128).
// ---------------------------------------------------------------------------
template <int N, bool TOUT>
__global__ __launch_bounds__(256) void rpe_layer_k(
    const float* __restrict__ X,
    const u16* __restrict__ wtA, const u16* __restrict__ wtB,
    const float* __restrict__ bA, const float* __restrict__ bB,
    float* __restrict__ outA, float* __restrict__ outB) {
  constexpr int NSL = N / 64;
  const int mlp = blockIdx.x / NSL;
  const int n0  = (blockIdx.x % NSL) * 64;
  const u16* WT = mlp ? wtB : wtA;
  const float* bias = mlp ? bB : bA;
  float* out = mlp ? outB : outA;
  const float* Xm = X + (size_t)mlp * 128 * 512;

  __shared__ __align__(16) u16 Bs[64 * 512];
  __shared__ __align__(16) u16 As[2][128 * 64];
  __shared__ float scale[128];

  const int tid  = threadIdx.x;
  const int lane = tid & 63;
  const int w    = tid >> 6;
  const int fl   = lane & 15, fh = lane >> 4;

#pragma unroll
  for (int r = 0; r < 16; r++) {
    int row  = r * 4 + w;
    int csrc = (lane & ~7) | ((lane & 7) ^ (row & 7));
    gload_lds16(WT + (size_t)(n0 + row) * 512 + csrc * 8,
                Bs + row * 512 + lane * 8);
  }

  {
    int row = tid >> 1, half = tid & 1;
    const float* xr = Xm + (size_t)row * 512 + half * 256;
    float ss = 0.f;
#pragma unroll 8
    for (int q = 0; q < 64; q++) {
      f32x4 v = *(const f32x4*)(xr + q * 4);
      ss += v[0] * v[0] + v[1] * v[1] + v[2] * v[2] + v[3] * v[3];
    }
    ss += __shfl_xor(ss, 1);
    if (!half) scale[row] = rsqrtf(ss * (1.f / 512.f) + 1e-6f);
  }
  __syncthreads();

  int arow[4], akc[4];
  float s_[4];
#pragma unroll
  for (int q = 0; q < 4; q++) {
    int cid = q * 256 + tid;
    arow[q] = cid >> 3;
    akc[q]  = cid & 7;
    s_[q]   = scale[arow[q]];
  }

#pragma unroll
  for (int q = 0; q < 4; q++) {
    const float* xp = Xm + (size_t)arow[q] * 512 + akc[q] * 8;
    f32x4 v0 = *(const f32x4*)xp;
    f32x4 v1 = *(const f32x4*)(xp + 4);
    u16x8 pk;
#pragma unroll
    for (int e = 0; e < 4; e++) pk[e]     = f2bf(fmaxf(v0[e], 0.f) * s_[q]);
#pragma unroll
    for (int e = 0; e < 4; e++) pk[4 + e] = f2bf(fmaxf(v1[e], 0.f) * s_[q]);
    *(u16x8*)(&As[0][arow[q] * 64 + ((akc[q] ^ (arow[q] & 7)) * 8)]) = pk;
  }
  __syncthreads();

  f32x4 acc[2][4];
  {
    f32x4 z = {0.f, 0.f, 0.f, 0.f};
#pragma unroll
    for (int i = 0; i < 2; i++)
#pragma unroll
      for (int j = 0; j < 4; j++) acc[i][j] = z;
  }

  for (int kti = 0; kti < 8; kti++) {
    const int cur = kti & 1;
    f32x4 pf0[4], pf1[4];
    if (kti < 7) {
#pragma unroll
      for (int q = 0; q < 4; q++) {
        const float* xp = Xm + (size_t)arow[q] * 512 + (kti + 1) * 64 + akc[q] * 8;
        pf0[q] = *(const f32x4*)xp;
        pf1[q] = *(const f32x4*)(xp + 4);
      }
    }
#pragma unroll
    for (int ks = 0; ks < 2; ks++) {
      const int xc = ((ks * 4 + fh) ^ (fl & 7)) * 8;
      s16x8 af[2], bfr[4];
#pragma unroll
      for (int i = 0; i < 2; i++)
        af[i] = *(const s16x8*)(&As[cur][(w * 32 + i * 16 + fl) * 64 + xc]);
#pragma unroll
      for (int j = 0; j < 4; j++)
        bfr[j] = *(const s16x8*)(&Bs[(j * 16 + fl) * 512 + kti * 64 + xc]);
#pragma unroll
      for (int i = 0; i < 2; i++)
#pragma unroll
        for (int j = 0; j < 4; j++)
          acc[i][j] = __builtin_amdgcn_mfma_f32_16x16x32_bf16(af[i], bfr[j], acc[i][j], 0, 0, 0);
    }
    if (kti < 7) {
#pragma unroll
      for (int q = 0; q < 4; q++) {
        u16x8 pk;
#pragma unroll
        for (int e = 0; e < 4; e++) pk[e]     = f2bf(fmaxf(pf0[q][e], 0.f) * s_[q]);
#pragma unroll
        for (int e = 0; e < 4; e++) pk[4 + e] = f2bf(fmaxf(pf1[q][e], 0.f) * s_[q]);
        *(u16x8*)(&As[cur ^ 1][arow[q] * 64 + ((akc[q] ^ (arow[q] & 7)) * 8)]) = pk;
      }
    }
    __syncthreads();
  }

#pragma unroll
  for (int i = 0; i < 2; i++)
#pragma unroll
    for (int j = 0; j < 4; j++) {
      int c = n0 + j * 16 + fl;
      float bv_ = bias[c];
#pragma unroll
      for (int q = 0; q < 4; q++) {
        int r = w * 32 + i * 16 + fh * 4 + q;
        if (TOUT) out[(size_t)c * 128 + r] = acc[i][j][q] + bv_;
        else      out[(size_t)r * N + c]   = acc[i][j][q] + bv_;
      }
    }
}

// ---------------------------------------------------------------------------
// gemm0_k (R7): [u|v] projection, 128(M) x 256(N) tile, BK=64, 512 thr
// (8 waves 2m x 4n), XOR-swizzled LDS, pre-swizzled gload_lds sources.
// Epilogue in 4 (mh,nh) rounds through epi[64][133]; silu(C+bias) ->
// uT (n<768) / vT, both (C,M).
// ---------------------------------------------------------------------------
__global__ __launch_bounds__(512) void gemm0_k(
    const u16* __restrict__ A, const u16* __restrict__ Bt,
    u16* __restrict__ u_out, u16* __restrict__ vt_out,
    const float* __restrict__ bu, const float* __restrict__ bv) {
  __shared__ __align__(16) char smem[49152];
  u16*   As  = (u16*)smem;              // 128 x 64 (16 KB)
  u16*   Bs  = As + 128 * 64;           // 256 x 64 (32 KB)
  float* epi = (float*)smem;            // 64 x 133 fp32 (34 KB, aliases)

  const int tid  = threadIdx.x;
  const int lane = tid & 63;
  const int wid  = tid >> 6;        // 0..7
  const int wm   = wid >> 2;        // 0..1
  const int wn   = wid & 3;         // 0..3
  const int bm   = blockIdx.x & 255, bn = blockIdx.x >> 8;
  const int m0   = bm * 128, n0 = bn * 256;
  const int fl   = lane & 15, fh = lane >> 4;
  const int K    = 384;

  f32x4 acc[4][4];
  {
    f32x4 z = {0.f, 0.f, 0.f, 0.f};
#pragma unroll
    for (int i = 0; i < 4; i++)
#pragma unroll
      for (int j = 0; j < 4; j++) acc[i][j] = z;
  }

  const int ra = tid >> 3;          // 0..63
  const int ca = tid & 7;
  const int swc = (ca ^ (ra & 7)) * 8;   // same for all staged rows (row&7 == ra&7)

  for (int kt = 0; kt < K; kt += 64) {
    // A: rows ra, ra+64
    gload_lds16(A + (size_t)(m0 + ra) * K + kt + swc,        As + ra * 64 + ca * 8);
    gload_lds16(A + (size_t)(m0 + 64 + ra) * K + kt + swc,   As + (64 + ra) * 64 + ca * 8);
    // B: rows ra, ra+64, ra+128, ra+192
#pragma unroll
    for (int q = 0; q < 4; q++)
      gload_lds16(Bt + (size_t)(n0 + q * 64 + ra) * K + kt + swc,
                  Bs + (q * 64 + ra) * 64 + ca * 8);
    __syncthreads();
#pragma unroll
    for (int ks = 0; ks < 2; ks++) {
      s16x8 af[4], bfr[4];
      const int xc = ((ks * 4 + fh) ^ (fl & 7)) * 8;
      const u16* ap = As + (wm * 64 + fl) * 64 + xc;
      const u16* bp = Bs + (wn * 64 + fl) * 64 + xc;
#pragma unroll
      for (int i = 0; i < 4; i++) af[i] = *(const s16x8*)(ap + i * 16 * 64);
#pragma unroll
      for (int j = 0; j < 4; j++) bfr[j] = *(const s16x8*)(bp + j * 16 * 64);
#pragma unroll
      for (int i = 0; i < 4; i++)
#pragma unroll
        for (int j = 0; j < 4; j++)
          acc[i][j] = __builtin_amdgcn_mfma_f32_16x16x32_bf16(af[i], bfr[j], acc[i][j], 0, 0, 0);
    }
    __syncthreads();
  }

  // ---- epilogue: 4 rounds (mh = m-half, nh = n-half of 128) ----
#pragma unroll
  for (int mh = 0; mh < 2; mh++) {
#pragma unroll
    for (int nh = 0; nh < 2; nh++) {
      __syncthreads();
      if (wm == mh && (wn >> 1) == nh) {
        int nq = wn & 1;
#pragma unroll
        for (int i = 0; i < 4; i++)
#pragma unroll
          for (int j = 0; j < 4; j++) {
            int er = i * 16 + fh * 4;
            int ec = nq * 64 + j * 16 + fl;
#pragma unroll
            for (int q = 0; q < 4; q++) epi[(er + q) * 133 + ec] = acc[i][j][q];
          }
      }
      __syncthreads();
      int cc = tid >> 2;                  // 0..127
      int cg = n0 + nh * 128 + cc;
      const bool isU = (cg < 768);
      const int cgm = isU ? cg : cg - 768;
      const float bias_v = (isU ? bu : bv)[cgm];
      u16* dst = (isU ? u_out : vt_out) + (size_t)cgm * M_TOT + m0 + mh * 64 + (tid & 3) * 16;
      u16x8 pk0, pk1;
      const int mb = (tid & 3) * 16;
#pragma unroll
      for (int e = 0; e < 8; e++) {
        pk0[e] = f2bf(silu_f(epi[(mb + e) * 133 + cc] + bias_v));
        pk1[e] = f2bf(silu_f(epi[(mb + 8 + e) * 133 + cc] + bias_v));
      }
      *(u16x8*)dst = pk0;
      *(u16x8*)(dst + 8) = pk1;
    }
  }
}

// ---------------------------------------------------------------------------
// gemm2_k: out[m][n] = sum_k gT[k][m]*Wot[n][k] + bo[n] + x[m][n].
// Tile 128(M) x 384(N=full), BK=64, 512 threads (8 waves: 2m x 4n).
// ---------------------------------------------------------------------------
__global__ __launch_bounds__(512, 2) void gemm2_k(
    const u16* __restrict__ gT, const u16* __restrict__ Wot,
    float* __restrict__ out, const float* __restrict__ bo,
    const float* __restrict__ xres) {
  __shared__ __align__(16) u16 As[128 * 64];
  __shared__ __align__(16) u16 Bs[384 * 64];

  const int tid  = threadIdx.x;
  const int lane = tid & 63;
  const int wid  = tid >> 6;
  const int wm   = wid >> 2;
  const int wn   = wid & 3;
  const int m0   = blockIdx.x * 128;
  const int fl   = lane & 15, fh = lane >> 4;

  f32x4 acc[4][6];
  {
    f32x4 z = {0.f, 0.f, 0.f, 0.f};
#pragma unroll
    for (int i = 0; i < 4; i++)
#pragma unroll
      for (int j = 0; j < 6; j++) acc[i][j] = z;
  }

  const int sr  = tid >> 3;
  const int scl = (tid & 7) * 8;
  const int scs = ((tid & 7) ^ (sr & 7)) * 8;

  for (int kt = 0; kt < 768; kt += 64) {
#pragma unroll
    for (int i = 0; i < 6; i++)
      gload_lds16(Wot + (size_t)(sr + 64 * i) * 768 + kt + scs,
                  Bs + (sr + 64 * i) * 64 + scl);
#pragma unroll
    for (int r = 0; r < 2; r++) {
      int cid = r * 512 + tid;
      int row = cid >> 4;
      int cm  = cid & 15;
      const u16* ga = gT + (size_t)(kt + row) * M_TOT + m0 + cm * 8;
      u16x8 rv = *(const u16x8*)ga;
      int kc = row >> 3, of = row & 7;
#pragma unroll
      for (int e = 0; e < 8; e++)
        As[(cm * 8 + e) * 64 + ((kc ^ e) << 3) + of] = rv[e];
    }
    __syncthreads();
#pragma unroll
    for (int ks = 0; ks < 2; ks++) {
      s16x8 af[4], bfr[6];
      const int xc = ((ks * 4 + fh) ^ (fl & 7)) * 8;
      const u16* ap = As + (wm * 64 + fl) * 64 + xc;
      const u16* bp = Bs + (wn * 96 + fl) * 64 + xc;
#pragma unroll
      for (int i = 0; i < 4; i++) af[i] = *(const s16x8*)(ap + i * 16 * 64);
#pragma unroll
      for (int j = 0; j < 6; j++) bfr[j] = *(const s16x8*)(bp + j * 16 * 64);
#pragma unroll
      for (int i = 0; i < 4; i++)
#pragma unroll
        for (int j = 0; j < 6; j++)
          acc[i][j] = __builtin_amdgcn_mfma_f32_16x16x32_bf16(af[i], bfr[j], acc[i][j], 0, 0, 0);
    }
    __syncthreads();
  }

  float bov[6];
#pragma unroll
  for (int j = 0; j < 6; j++) bov[j] = bo[wn * 96 + j * 16 + fl];
#pragma unroll
  for (int i = 0; i < 4; i++) {
#pragma unroll
    for (int q = 0; q < 4; q++) {
      int m = m0 + wm * 64 + i * 16 + fh * 4 + q;
      const float* xr = xres + (size_t)m * 384;
      float* orow = out + (size_t)m * 384;
#pragma unroll
      for (int j = 0; j < 6; j++) {
        int n = wn * 96 + j * 16 + fl;
        orow[n] = acc[i][j][q] + bov[j] + xr[n];
      }
    }
  }
}

// ---------------------------------------------------------------------------
// conv_k: MFMA Toeplitz conv + u-gate.  Block = channel c (grid 768),
// loops b=0..7 with T14 register prefetch of next batch's V/U.
// ---------------------------------------------------------------------------
__global__ __launch_bounds__(256) void conv_k(const u16* __restrict__ vt,
                                              const u16* __restrict__ ut,
                                              const float* __restrict__ a_hT,
                                              const float* __restrict__ a_wT,
                                              u16* __restrict__ gT) {
  __shared__ __align__(16) u16 Th[64 * 72];
  __shared__ __align__(16) u16 Tw[64 * 72];
  __shared__ __align__(16) u16 Vs[64 * 72];
  __shared__ __align__(16) u16 VTs[64 * 72];
  __shared__ __align__(16) u16 Us[64 * 72];
  __shared__ float ahr[192];
  __shared__ float awr[192];
  u16* epi = VTs;

  const int tid = threadIdx.x;
  const int c = blockIdx.x;
  const int lane = tid & 63, w = tid >> 6;
  const int fl = lane & 15, fh = lane >> 4;

  if (tid < 192) {
    int idx = (128 - tid) & 127;
    ahr[tid] = a_hT[(size_t)c * 128 + idx];
    awr[tid] = a_wT[(size_t)c * 128 + idx];
  }
  __syncthreads();

  {
    int y = tid & 63, j0 = (tid >> 6) * 16;
    int base = 128 - y + j0;
    u16x8 p0, p1, q0, q1;
#pragma unroll
    for (int e = 0; e < 8; e++) {
      p0[e] = f2bf(ahr[base + e]);
      p1[e] = f2bf(ahr[base + 8 + e]);
      q0[e] = f2bf(awr[base + e]);
      q1[e] = f2bf(awr[base + 8 + e]);
    }
    *(u16x8*)(Th + y * 72 + j0)     = p0;
    *(u16x8*)(Th + y * 72 + j0 + 8) = p1;
    *(u16x8*)(Tw + y * 72 + j0)     = q0;
    *(u16x8*)(Tw + y * 72 + j0 + 8) = q1;
  }

  const int sy = tid >> 2, sx = (tid & 3) * 16;
  const int ty = tid & 63, tj = (tid >> 6) * 16;

  const u16* srcv0 = vt + (size_t)c * M_TOT;
  const u16* srcu0 = ut + (size_t)c * M_TOT;

  // prefetch b=0 into registers
  u16x8 pv0 = *(const u16x8*)(srcv0 + sy * 64 + sx);
  u16x8 pv1 = *(const u16x8*)(srcv0 + sy * 64 + sx + 8);
  u16x8 pu0 = *(const u16x8*)(srcu0 + sy * 64 + sx);
  u16x8 pu1 = *(const u16x8*)(srcu0 + sy * 64 + sx + 8);

  for (int b = 0; b < 8; b++) {
    // publish regs to LDS
    *(u16x8*)(Vs + sy * 72 + sx)     = pv0;
    *(u16x8*)(Vs + sy * 72 + sx + 8) = pv1;
    *(u16x8*)(Us + sy * 72 + sx)     = pu0;
    *(u16x8*)(Us + sy * 72 + sx + 8) = pu1;
    __syncthreads();

    // issue next-batch loads (latency hides under VT build + MFMA + gate)
    if (b < 7) {
      const u16* nv = srcv0 + (b + 1) * 4096 + sy * 64 + sx;
      const u16* nu = srcu0 + (b + 1) * 4096 + sy * 64 + sx;
      pv0 = *(const u16x8*)nv;
      pv1 = *(const u16x8*)(nv + 8);
      pu0 = *(const u16x8*)nu;
      pu1 = *(const u16x8*)(nu + 8);
    }

    {
      u16x8 q0 = *(const u16x8*)(Vs + ty * 72 + tj);
      u16x8 q1 = *(const u16x8*)(Vs + ty * 72 + tj + 8);
#pragma unroll
      for (int e = 0; e < 8; e++) VTs[(tj + e) * 72 + ty]     = q0[e];
#pragma unroll
      for (int e = 0; e < 8; e++) VTs[(tj + 8 + e) * 72 + ty] = q1[e];
    }
    __syncthreads();

    f32x4 acc[4];
    {
      f32x4 z = {0.f, 0.f, 0.f, 0.f};
#pragma unroll
      for (int i = 0; i < 4; i++) acc[i] = z;
    }
#pragma unroll
    for (int ks = 0; ks < 2; ks++) {
      s16x8 qh = *(const s16x8*)(Th + (w * 16 + fl) * 72 + ks * 32 + fh * 8);
#pragma unroll
      for (int i = 0; i < 4; i++) {
        s16x8 p = *(const s16x8*)(VTs + (i * 16 + fl) * 72 + ks * 32 + fh * 8);
        acc[i] = __builtin_amdgcn_mfma_f32_16x16x32_bf16(p, qh, acc[i], 0, 0, 0);
      }
      s16x8 qw = *(const s16x8*)(Vs + (w * 16 + fl) * 72 + ks * 32 + fh * 8);
#pragma unroll
      for (int i = 0; i < 4; i++) {
        s16x8 p = *(const s16x8*)(Tw + (i * 16 + fl) * 72 + ks * 32 + fh * 8);
        acc[i] = __builtin_amdgcn_mfma_f32_16x16x32_bf16(p, qw, acc[i], 0, 0, 0);
      }
    }
    __syncthreads();

    {
      int y = w * 16 + fl;
#pragma unroll
      for (int i = 0; i < 4; i++) {
        u16x4 uq = *(const u16x4*)(Us + y * 72 + i * 16 + fh * 4);
        u16x4 pk;
#pragma unroll
        for (int e = 0; e < 4; e++) pk[e] = f2bf(acc[i][e] * bf2f(uq[e]));
        *(u16x4*)(epi + y * 72 + i * 16 + fh * 4) = pk;
      }
    }
    __syncthreads();

    {
      u16x8 a0 = *(const u16x8*)(epi + sy * 72 + sx);
      u16x8 a1 = *(const u16x8*)(epi + sy * 72 + sx + 8);
      u16* dst = gT + (size_t)c * M_TOT + b * 4096 + sy * 64 + sx;
      *(u16x8*)dst = a0;
      *(u16x8*)(dst + 8) = a1;
    }
    __syncthreads();
  }
}

// ---------------------------------------------------------------------------
extern "C" void kernel_launch(void* const* d_in, const int* in_sizes, int n_in,
                              void* d_out, int out_size, void* d_ws, size_t ws_size,
                              hipStream_t stream) {
  const float* x    = (const float*)d_in[0];
  const float* Wu   = (const float*)d_in[3];
  const float* bu   = (const float*)d_in[4];
  const float* Wv   = (const float*)d_in[5];
  const float* bv   = (const float*)d_in[6];
  const float* Wo   = (const float*)d_in[7];
  const float* bo   = (const float*)d_in[8];
  const float* r1pw = (const float*)d_in[9];
  const float* r1pb = (const float*)d_in[10];
  const float* r1lw = (const float*)d_in[11];
  const float* r1lb = (const float*)d_in[12];
  const float* r1ow = (const float*)d_in[13];
  const float* r1ob = (const float*)d_in[14];
  const float* r2pw = (const float*)d_in[15];
  const float* r2pb = (const float*)d_in[16];
  const float* r2lw = (const float*)d_in[17];
  const float* r2lb = (const float*)d_in[18];
  const float* r2ow = (const float*)d_in[19];
  const float* r2ob = (const float*)d_in[20];
  float* outp = (float*)d_out;

  char* ws = (char*)d_ws;
  size_t off = 0;
  auto carve = [&](size_t bytes) {
    char* p = ws + off;
    off += (bytes + 255) & ~(size_t)255;
    return p;
  };
  u16*   xn   = (u16*)carve((size_t)M_TOT * 384 * 2);
  u16*   uT   = (u16*)carve((size_t)768 * M_TOT * 2);
  u16*   vT   = (u16*)carve((size_t)768 * M_TOT * 2);
  u16*   gT   = (u16*)carve((size_t)768 * M_TOT * 2);
  u16*   Wuvt = (u16*)carve((size_t)1536 * 384 * 2);
  u16*   Wot  = (u16*)carve((size_t)384 * 768 * 2);
  float* awT  = (float*)carve((size_t)768 * 128 * 4);
  float* ahT  = (float*)carve((size_t)768 * 128 * 4);

  // RPE scratch aliased into gT region (gT written only later, by conv_k)
  char* rb  = (char*)gT;
  u16*   lwT = (u16*)rb;                               // 3 MB
  u16*   owT = (u16*)(rb + 3145728);                   // 1.5 MB
  float* X0  = (float*)(rb + 3145728 + 1572864);
  float* X1  = X0 + 256 * 512;

  setup_k<<<11488, 256, 0, stream>>>(x, xn, Wu, Wv, Wo, Wuvt, Wot,
                                     r1lw, r1ow, r2lw, r2ow, lwT, owT,
                                     r1pw, r1pb, r2pw, r2pb, X0);

  // RPE layers 1-3 fused (X0 -> X1 -> X0 -> X1)
  rpe_all_k<<<2, 1024, 0, stream>>>(X0, X1, lwT, r1lb, r2lb);
  // final projection (N=768) -> transposed coeff tables
  rpe_layer_k<768, true><<<24, 256, 0, stream>>>(X1, owT, owT + 393216,
                                                 r1ob, r2ob, awT, ahT);

  // u|v GEMM: M=32768, N=1536, K=384 -> uT, vT (both (C,M))
  gemm0_k<<<256 * 6, 512, 0, stream>>>(xn, Wuvt, uT, vT, bu, bv);
  // conv + gate -> gT (C,M); block = channel
  conv_k<<<768, 256, 0, stream>>>(vT, uT, ahT, awT, gT);
  // out GEMM: M=32768, N=384(full), K=768 (+bo +x residual)
  gemm2_k<<<256, 512, 0, stream>>>(gT, Wot, outp, bo, x);
}

// Round 8
// 384.564 us; speedup vs baseline: 1.2443x; 1.2443x over previous
//
#include <hip/hip_runtime.h>
#include <stdint.h>

// ---------------------------------------------------------------------------
// GTU block: rmsnorm -> [u|v] GEMM+silu -> depthwise 2D circular Toeplitz conv
//            -> gate -> out = g@Wo + bo + x
// R8: (a) REVERT rpe fusion (R7's grid-2 monster: 147us @ 0.36% occupancy)
//     back to R6 per-layer kernels (grid 16/16/16/24).
//     (b) conv_k: 5->4 barriers per batch iteration.
//     (c) gemm2_k: T14 issue-early/write-late A staging (reads overlap MFMA).
// ---------------------------------------------------------------------------

typedef __attribute__((ext_vector_type(4))) float  f32x4;
typedef __attribute__((ext_vector_type(8))) short  s16x8;
typedef __attribute__((ext_vector_type(8))) unsigned short u16x8;
typedef __attribute__((ext_vector_type(4))) unsigned short u16x4;
typedef unsigned short u16;

#define M_TOT 32768      // B*H*W

__device__ __forceinline__ u16 f2bf(float f) {
  union { float f; unsigned int u; } v; v.f = f;
  unsigned int r = (v.u + 0x7FFFu + ((v.u >> 16) & 1u)) >> 16;
  return (u16)r;
}
__device__ __forceinline__ float bf2f(u16 h) {
  union { unsigned int u; float f; } v; v.u = ((unsigned int)h) << 16;
  return v.f;
}
__device__ __forceinline__ float silu_f(float x) {
  return x * __builtin_amdgcn_rcpf(1.f + __expf(-x));
}

__device__ __forceinline__ void gload_lds16(const u16* g, u16* l) {
  __builtin_amdgcn_global_load_lds(
      (const __attribute__((address_space(1))) uint32_t*)g,
      (__attribute__((address_space(3))) uint32_t*)l, 16, 0, 0);
}

// ---------------------------------------------------------------------------
// setup_k: blockIdx-partitioned fusion (rmsnorm | weight transposes | rpe-in)
// ---------------------------------------------------------------------------
__global__ __launch_bounds__(256) void setup_k(
    const float* __restrict__ x, u16* __restrict__ xn,
    const float* __restrict__ Wu, const float* __restrict__ Wv,
    const float* __restrict__ Wo, u16* __restrict__ Wuvt, u16* __restrict__ Wot,
    const float* __restrict__ r1lw, const float* __restrict__ r1ow,
    const float* __restrict__ r2lw, const float* __restrict__ r2ow,
    u16* __restrict__ lwT, u16* __restrict__ owT,
    const float* __restrict__ r1pw, const float* __restrict__ r1pb,
    const float* __restrict__ r2pw, const float* __restrict__ r2pb,
    float* __restrict__ X0) {
  __shared__ float sm[32][33];
  const int bid = blockIdx.x;
  const int tid = threadIdx.x;

  if (bid < 8192) {                     // ---- rmsnorm ----
    int row  = bid * 4 + (tid >> 6);
    int lane = tid & 63;
    const float* xr = x + (size_t)row * 384 + lane;
    float v[6]; float ss = 0.f;
#pragma unroll
    for (int i = 0; i < 6; i++) { v[i] = xr[i * 64]; ss += v[i] * v[i]; }
#pragma unroll
    for (int off = 32; off > 0; off >>= 1) ss += __shfl_xor(ss, off);
    float sc = rsqrtf(ss * (1.f / 384.f) + 1e-6f);
    u16* o = xn + (size_t)row * 384 + lane;
#pragma unroll
    for (int i = 0; i < 6; i++) o[i * 64] = f2bf(v[i] * sc);
  } else if (bid < 11360) {             // ---- tiled transposes ----
    int b = bid - 8192;
    const float* src; u16* dst; int C, DS, R0, C0;
    if (b < 2304) {
      int mlp = b / 1152, r = b % 1152;
      if (r < 768) {
        int L = r / 256, t = r % 256;
        R0 = (t / 16) * 32; C0 = (t % 16) * 32;
        src = (mlp ? r2lw : r1lw) + (size_t)L * 262144;
        dst = lwT + (size_t)(mlp * 3 + L) * 262144;
        C = 512; DS = 512;
      } else {
        int t = r - 768;
        R0 = (t / 24) * 32; C0 = (t % 24) * 32;
        src = mlp ? r2ow : r1ow;
        dst = owT + (size_t)mlp * 393216;
        C = 768; DS = 512;
      }
    } else {
      int t = b - 2304;
      if (t < 288)      { R0 = (t / 24) * 32; C0 = (t % 24) * 32;
                          src = Wu; C = 768; dst = Wuvt;             DS = 384; }
      else if (t < 576) { int t2 = t - 288; R0 = (t2 / 24) * 32; C0 = (t2 % 24) * 32;
                          src = Wv; C = 768; dst = Wuvt + 768 * 384; DS = 384; }
      else              { int t2 = t - 576; R0 = (t2 / 12) * 32; C0 = (t2 % 12) * 32;
                          src = Wo; C = 384; dst = Wot;              DS = 768; }
    }
    int lx = tid % 32, ly = tid / 32;
#pragma unroll
    for (int q = 0; q < 4; q++) {
      int y = q * 8 + ly;
      sm[y][lx] = src[(size_t)(R0 + y) * C + C0 + lx];
    }
    __syncthreads();
#pragma unroll
    for (int q = 0; q < 4; q++) {
      int y = q * 8 + ly;
      dst[(size_t)(C0 + y) * DS + R0 + lx] = f2bf(sm[lx][y]);
    }
  } else {                              // ---- rpe input layer ----
    int idx = (bid - 11360) * 256 + tid;
    int gid = idx * 4;
    int row = gid >> 9, col = gid & 511;
    int mlp = row >> 7, p = row & 127;
    float pos = (p < 64) ? (float)p : ((p == 64) ? 0.f : (float)(p - 128));
    const float* pw = (mlp ? r2pw : r1pw) + col;
    const float* pb = (mlp ? r2pb : r1pb) + col;
    f32x4 w = *(const f32x4*)pw;
    f32x4 bb = *(const f32x4*)pb;
    f32x4 o;
#pragma unroll
    for (int e = 0; e < 4; e++) o[e] = fmaxf(pos * w[e] + bb[e], 0.f);
    *(f32x4*)(X0 + gid) = o;
  }
}

// ---------------------------------------------------------------------------
// RPE layer GEMM (R6 design).  X (128x512 fp32 per mlp) -> relu(srms(X)) @
// WT^T + b.  grid = 2*(N/64); block owns 128(M) x 64(N), full K=512.
// B-slice (64x512, 64KB) staged ONCE via gload_lds burst (pre-swizzled src);
// A double-buffered, reg-prefetched, swizzled.  TOUT: store (C,128).
// ---------------------------------------------------------------------------
template <int N, bool TOUT>
__global__ __launch_bounds__(256) void rpe_layer_k(
    const float* __restrict__ X,
    const u16* __restrict__ wtA, const u16* __restrict__ wtB,
    const float* __restrict__ bA, const float* __restrict__ bB,
    float* __restrict__ outA, float* __restrict__ outB) {
  constexpr int NSL = N / 64;
  const int mlp = blockIdx.x / NSL;
  const int n0  = (blockIdx.x % NSL) * 64;
  const u16* WT = mlp ? wtB : wtA;
  const float* bias = mlp ? bB : bA;
  float* out = mlp ? outB : outA;
  const float* Xm = X + (size_t)mlp * 128 * 512;

  __shared__ __align__(16) u16 Bs[64 * 512];
  __shared__ __align__(16) u16 As[2][128 * 64];
  __shared__ float scale[128];

  const int tid  = threadIdx.x;
  const int lane = tid & 63;
  const int w    = tid >> 6;
  const int fl   = lane & 15, fh = lane >> 4;

#pragma unroll
  for (int r = 0; r < 16; r++) {
    int row  = r * 4 + w;
    int csrc = (lane & ~7) | ((lane & 7) ^ (row & 7));
    gload_lds16(WT + (size_t)(n0 + row) * 512 + csrc * 8,
                Bs + row * 512 + lane * 8);
  }

  {
    int row = tid >> 1, half = tid & 1;
    const float* xr = Xm + (size_t)row * 512 + half * 256;
    float ss = 0.f;
#pragma unroll 8
    for (int q = 0; q < 64; q++) {
      f32x4 v = *(const f32x4*)(xr + q * 4);
      ss += v[0] * v[0] + v[1] * v[1] + v[2] * v[2] + v[3] * v[3];
    }
    ss += __shfl_xor(ss, 1);
    if (!half) scale[row] = rsqrtf(ss * (1.f / 512.f) + 1e-6f);
  }
  __syncthreads();

  int arow[4], akc[4];
  float s_[4];
#pragma unroll
  for (int q = 0; q < 4; q++) {
    int cid = q * 256 + tid;
    arow[q] = cid >> 3;
    akc[q]  = cid & 7;
    s_[q]   = scale[arow[q]];
  }

#pragma unroll
  for (int q = 0; q < 4; q++) {
    const float* xp = Xm + (size_t)arow[q] * 512 + akc[q] * 8;
    f32x4 v0 = *(const f32x4*)xp;
    f32x4 v1 = *(const f32x4*)(xp + 4);
    u16x8 pk;
#pragma unroll
    for (int e = 0; e < 4; e++) pk[e]     = f2bf(fmaxf(v0[e], 0.f) * s_[q]);
#pragma unroll
    for (int e = 0; e < 4; e++) pk[4 + e] = f2bf(fmaxf(v1[e], 0.f) * s_[q]);
    *(u16x8*)(&As[0][arow[q] * 64 + ((akc[q] ^ (arow[q] & 7)) * 8)]) = pk;
  }
  __syncthreads();

  f32x4 acc[2][4];
  {
    f32x4 z = {0.f, 0.f, 0.f, 0.f};
#pragma unroll
    for (int i = 0; i < 2; i++)
#pragma unroll
      for (int j = 0; j < 4; j++) acc[i][j] = z;
  }

  for (int kti = 0; kti < 8; kti++) {
    const int cur = kti & 1;
    f32x4 pf0[4], pf1[4];
    if (kti < 7) {
#pragma unroll
      for (int q = 0; q < 4; q++) {
        const float* xp = Xm + (size_t)arow[q] * 512 + (kti + 1) * 64 + akc[q] * 8;
        pf0[q] = *(const f32x4*)xp;
        pf1[q] = *(const f32x4*)(xp + 4);
      }
    }
#pragma unroll
    for (int ks = 0; ks < 2; ks++) {
      const int xc = ((ks * 4 + fh) ^ (fl & 7)) * 8;
      s16x8 af[2], bfr[4];
#pragma unroll
      for (int i = 0; i < 2; i++)
        af[i] = *(const s16x8*)(&As[cur][(w * 32 + i * 16 + fl) * 64 + xc]);
#pragma unroll
      for (int j = 0; j < 4; j++)
        bfr[j] = *(const s16x8*)(&Bs[(j * 16 + fl) * 512 + kti * 64 + xc]);
#pragma unroll
      for (int i = 0; i < 2; i++)
#pragma unroll
        for (int j = 0; j < 4; j++)
          acc[i][j] = __builtin_amdgcn_mfma_f32_16x16x32_bf16(af[i], bfr[j], acc[i][j], 0, 0, 0);
    }
    if (kti < 7) {
#pragma unroll
      for (int q = 0; q < 4; q++) {
        u16x8 pk;
#pragma unroll
        for (int e = 0; e < 4; e++) pk[e]     = f2bf(fmaxf(pf0[q][e], 0.f) * s_[q]);
#pragma unroll
        for (int e = 0; e < 4; e++) pk[4 + e] = f2bf(fmaxf(pf1[q][e], 0.f) * s_[q]);
        *(u16x8*)(&As[cur ^ 1][arow[q] * 64 + ((akc[q] ^ (arow[q] & 7)) * 8)]) = pk;
      }
    }
    __syncthreads();
  }

#pragma unroll
  for (int i = 0; i < 2; i++)
#pragma unroll
    for (int j = 0; j < 4; j++) {
      int c = n0 + j * 16 + fl;
      float bv_ = bias[c];
#pragma unroll
      for (int q = 0; q < 4; q++) {
        int r = w * 32 + i * 16 + fh * 4 + q;
        if (TOUT) out[(size_t)c * 128 + r] = acc[i][j][q] + bv_;
        else      out[(size_t)r * N + c]   = acc[i][j][q] + bv_;
      }
    }
}

// ---------------------------------------------------------------------------
// gemm0_k: [u|v] projection, 128(M) x 256(N) tile, BK=64, 512 thr
// (8 waves 2m x 4n), XOR-swizzled LDS, pre-swizzled gload_lds sources.
// Epilogue: silu(C+bias) -> uT (n<768) / vT, both (C,M).
// ---------------------------------------------------------------------------
__global__ __launch_bounds__(512) void gemm0_k(
    const u16* __restrict__ A, const u16* __restrict__ Bt,
    u16* __restrict__ u_out, u16* __restrict__ vt_out,
    const float* __restrict__ bu, const float* __restrict__ bv) {
  __shared__ __align__(16) char smem[49152];
  u16*   As  = (u16*)smem;              // 128 x 64 (16 KB)
  u16*   Bs  = As + 128 * 64;           // 256 x 64 (32 KB)
  float* epi = (float*)smem;            // 64 x 133 fp32 (34 KB, aliases)

  const int tid  = threadIdx.x;
  const int lane = tid & 63;
  const int wid  = tid >> 6;
  const int wm   = wid >> 2;
  const int wn   = wid & 3;
  const int bm   = blockIdx.x & 255, bn = blockIdx.x >> 8;
  const int m0   = bm * 128, n0 = bn * 256;
  const int fl   = lane & 15, fh = lane >> 4;
  const int K    = 384;

  f32x4 acc[4][4];
  {
    f32x4 z = {0.f, 0.f, 0.f, 0.f};
#pragma unroll
    for (int i = 0; i < 4; i++)
#pragma unroll
      for (int j = 0; j < 4; j++) acc[i][j] = z;
  }

  const int ra = tid >> 3;
  const int ca = tid & 7;
  const int swc = (ca ^ (ra & 7)) * 8;

  for (int kt = 0; kt < K; kt += 64) {
    gload_lds16(A + (size_t)(m0 + ra) * K + kt + swc,        As + ra * 64 + ca * 8);
    gload_lds16(A + (size_t)(m0 + 64 + ra) * K + kt + swc,   As + (64 + ra) * 64 + ca * 8);
#pragma unroll
    for (int q = 0; q < 4; q++)
      gload_lds16(Bt + (size_t)(n0 + q * 64 + ra) * K + kt + swc,
                  Bs + (q * 64 + ra) * 64 + ca * 8);
    __syncthreads();
#pragma unroll
    for (int ks = 0; ks < 2; ks++) {
      s16x8 af[4], bfr[4];
      const int xc = ((ks * 4 + fh) ^ (fl & 7)) * 8;
      const u16* ap = As + (wm * 64 + fl) * 64 + xc;
      const u16* bp = Bs + (wn * 64 + fl) * 64 + xc;
#pragma unroll
      for (int i = 0; i < 4; i++) af[i] = *(const s16x8*)(ap + i * 16 * 64);
#pragma unroll
      for (int j = 0; j < 4; j++) bfr[j] = *(const s16x8*)(bp + j * 16 * 64);
#pragma unroll
      for (int i = 0; i < 4; i++)
#pragma unroll
        for (int j = 0; j < 4; j++)
          acc[i][j] = __builtin_amdgcn_mfma_f32_16x16x32_bf16(af[i], bfr[j], acc[i][j], 0, 0, 0);
    }
    __syncthreads();
  }

#pragma unroll
  for (int mh = 0; mh < 2; mh++) {
#pragma unroll
    for (int nh = 0; nh < 2; nh++) {
      __syncthreads();
      if (wm == mh && (wn >> 1) == nh) {
        int nq = wn & 1;
#pragma unroll
        for (int i = 0; i < 4; i++)
#pragma unroll
          for (int j = 0; j < 4; j++) {
            int er = i * 16 + fh * 4;
            int ec = nq * 64 + j * 16 + fl;
#pragma unroll
            for (int q = 0; q < 4; q++) epi[(er + q) * 133 + ec] = acc[i][j][q];
          }
      }
      __syncthreads();
      int cc = tid >> 2;
      int cg = n0 + nh * 128 + cc;
      const bool isU = (cg < 768);
      const int cgm = isU ? cg : cg - 768;
      const float bias_v = (isU ? bu : bv)[cgm];
      u16* dst = (isU ? u_out : vt_out) + (size_t)cgm * M_TOT + m0 + mh * 64 + (tid & 3) * 16;
      u16x8 pk0, pk1;
      const int mb = (tid & 3) * 16;
#pragma unroll
      for (int e = 0; e < 8; e++) {
        pk0[e] = f2bf(silu_f(epi[(mb + e) * 133 + cc] + bias_v));
        pk1[e] = f2bf(silu_f(epi[(mb + 8 + e) * 133 + cc] + bias_v));
      }
      *(u16x8*)dst = pk0;
      *(u16x8*)(dst + 8) = pk1;
    }
  }
}

// ---------------------------------------------------------------------------
// gemm2_k: out[m][n] = sum_k gT[k][m]*Wot[n][k] + bo[n] + x[m][n].
// Tile 128(M) x 384(N=full), BK=64, 512 threads (8 waves: 2m x 4n).
// R8: T14 A staging -- global reads for tile kt+1 issued right after the
// staging barrier of kt (in flight under MFMA), ds-scatter next iteration.
// ---------------------------------------------------------------------------
__global__ __launch_bounds__(512, 2) void gemm2_k(
    const u16* __restrict__ gT, const u16* __restrict__ Wot,
    float* __restrict__ out, const float* __restrict__ bo,
    const float* __restrict__ xres) {
  __shared__ __align__(16) u16 As[128 * 64];
  __shared__ __align__(16) u16 Bs[384 * 64];

  const int tid  = threadIdx.x;
  const int lane = tid & 63;
  const int wid  = tid >> 6;
  const int wm   = wid >> 2;
  const int wn   = wid & 3;
  const int m0   = blockIdx.x * 128;
  const int fl   = lane & 15, fh = lane >> 4;

  f32x4 acc[4][6];
  {
    f32x4 z = {0.f, 0.f, 0.f, 0.f};
#pragma unroll
    for (int i = 0; i < 4; i++)
#pragma unroll
      for (int j = 0; j < 6; j++) acc[i][j] = z;
  }

  const int sr  = tid >> 3;
  const int scl = (tid & 7) * 8;
  const int scs = ((tid & 7) ^ (sr & 7)) * 8;

  // A-staging coords (2 chunks/thread)
  int arw[2], acm[2];
#pragma unroll
  for (int r = 0; r < 2; r++) {
    int cid = r * 512 + tid;
    arw[r] = cid >> 4;          // k-row 0..63
    acm[r] = cid & 15;          // m-chunk
  }

  // preload A regs for kt=0
  u16x8 rv[2];
#pragma unroll
  for (int r = 0; r < 2; r++)
    rv[r] = *(const u16x8*)(gT + (size_t)arw[r] * M_TOT + m0 + acm[r] * 8);

  for (int kt = 0; kt < 768; kt += 64) {
#pragma unroll
    for (int i = 0; i < 6; i++)
      gload_lds16(Wot + (size_t)(sr + 64 * i) * 768 + kt + scs,
                  Bs + (sr + 64 * i) * 64 + scl);
    // scatter current A regs (swizzled transpose write)
#pragma unroll
    for (int r = 0; r < 2; r++) {
      int kc = arw[r] >> 3, of = arw[r] & 7;
#pragma unroll
      for (int e = 0; e < 8; e++)
        As[(acm[r] * 8 + e) * 64 + ((kc ^ e) << 3) + of] = rv[r][e];
    }
    __syncthreads();
    // issue next-tile A reads: latency hides under MFMA
    if (kt < 704) {
#pragma unroll
      for (int r = 0; r < 2; r++)
        rv[r] = *(const u16x8*)(gT + (size_t)(kt + 64 + arw[r]) * M_TOT + m0 + acm[r] * 8);
    }
#pragma unroll
    for (int ks = 0; ks < 2; ks++) {
      s16x8 af[4], bfr[6];
      const int xc = ((ks * 4 + fh) ^ (fl & 7)) * 8;
      const u16* ap = As + (wm * 64 + fl) * 64 + xc;
      const u16* bp = Bs + (wn * 96 + fl) * 64 + xc;
#pragma unroll
      for (int i = 0; i < 4; i++) af[i] = *(const s16x8*)(ap + i * 16 * 64);
#pragma unroll
      for (int j = 0; j < 6; j++) bfr[j] = *(const s16x8*)(bp + j * 16 * 64);
#pragma unroll
      for (int i = 0; i < 4; i++)
#pragma unroll
        for (int j = 0; j < 6; j++)
          acc[i][j] = __builtin_amdgcn_mfma_f32_16x16x32_bf16(af[i], bfr[j], acc[i][j], 0, 0, 0);
    }
    __syncthreads();
  }

  float bov[6];
#pragma unroll
  for (int j = 0; j < 6; j++) bov[j] = bo[wn * 96 + j * 16 + fl];
#pragma unroll
  for (int i = 0; i < 4; i++) {
#pragma unroll
    for (int q = 0; q < 4; q++) {
      int m = m0 + wm * 64 + i * 16 + fh * 4 + q;
      const float* xr = xres + (size_t)m * 384;
      float* orow = out + (size_t)m * 384;
#pragma unroll
      for (int j = 0; j < 6; j++) {
        int n = wn * 96 + j * 16 + fl;
        orow[n] = acc[i][j][q] + bov[j] + xr[n];
      }
    }
  }
}

// ---------------------------------------------------------------------------
// conv_k: MFMA Toeplitz conv + u-gate.  Block = channel c (grid 768),
// loops b=0..7; T14 reg prefetch; 4 barriers/iter (loop-end sync removed:
// store reads epi(=VTs) while next publish writes Vs/Us -- disjoint; next
// VT-build is fenced by the next iteration's first barrier).
// ---------------------------------------------------------------------------
__global__ __launch_bounds__(256) void conv_k(const u16* __restrict__ vt,
                                              const u16* __restrict__ ut,
                                              const float* __restrict__ a_hT,
                                              const float* __restrict__ a_wT,
                                              u16* __restrict__ gT) {
  __shared__ __align__(16) u16 Th[64 * 72];
  __shared__ __align__(16) u16 Tw[64 * 72];
  __shared__ __align__(16) u16 Vs[64 * 72];
  __shared__ __align__(16) u16 VTs[64 * 72];
  __shared__ __align__(16) u16 Us[64 * 72];
  __shared__ float ahr[192];
  __shared__ float awr[192];
  u16* epi = VTs;

  const int tid = threadIdx.x;
  const int c = blockIdx.x;
  const int lane = tid & 63, w = tid >> 6;
  const int fl = lane & 15, fh = lane >> 4;

  if (tid < 192) {
    int idx = (128 - tid) & 127;
    ahr[tid] = a_hT[(size_t)c * 128 + idx];
    awr[tid] = a_wT[(size_t)c * 128 + idx];
  }
  __syncthreads();

  {
    int y = tid & 63, j0 = (tid >> 6) * 16;
    int base = 128 - y + j0;
    u16x8 p0, p1, q0, q1;
#pragma unroll
    for (int e = 0; e < 8; e++) {
      p0[e] = f2bf(ahr[base + e]);
      p1[e] = f2bf(ahr[base + 8 + e]);
      q0[e] = f2bf(awr[base + e]);
      q1[e] = f2bf(awr[base + 8 + e]);
    }
    *(u16x8*)(Th + y * 72 + j0)     = p0;
    *(u16x8*)(Th + y * 72 + j0 + 8) = p1;
    *(u16x8*)(Tw + y * 72 + j0)     = q0;
    *(u16x8*)(Tw + y * 72 + j0 + 8) = q1;
  }

  const int sy = tid >> 2, sx = (tid & 3) * 16;
  const int ty = tid & 63, tj = (tid >> 6) * 16;

  const u16* srcv0 = vt + (size_t)c * M_TOT;
  const u16* srcu0 = ut + (size_t)c * M_TOT;

  u16x8 pv0 = *(const u16x8*)(srcv0 + sy * 64 + sx);
  u16x8 pv1 = *(const u16x8*)(srcv0 + sy * 64 + sx + 8);
  u16x8 pu0 = *(const u16x8*)(srcu0 + sy * 64 + sx);
  u16x8 pu1 = *(const u16x8*)(srcu0 + sy * 64 + sx + 8);

  for (int b = 0; b < 8; b++) {
    *(u16x8*)(Vs + sy * 72 + sx)     = pv0;
    *(u16x8*)(Vs + sy * 72 + sx + 8) = pv1;
    *(u16x8*)(Us + sy * 72 + sx)     = pu0;
    *(u16x8*)(Us + sy * 72 + sx + 8) = pu1;
    __syncthreads();                     // (1) Vs/Us ready; prev store done

    if (b < 7) {
      const u16* nv = srcv0 + (b + 1) * 4096 + sy * 64 + sx;
      const u16* nu = srcu0 + (b + 1) * 4096 + sy * 64 + sx;
      pv0 = *(const u16x8*)nv;
      pv1 = *(const u16x8*)(nv + 8);
      pu0 = *(const u16x8*)nu;
      pu1 = *(const u16x8*)(nu + 8);
    }

    {
      u16x8 q0 = *(const u16x8*)(Vs + ty * 72 + tj);
      u16x8 q1 = *(const u16x8*)(Vs + ty * 72 + tj + 8);
#pragma unroll
      for (int e = 0; e < 8; e++) VTs[(tj + e) * 72 + ty]     = q0[e];
#pragma unroll
      for (int e = 0; e < 8; e++) VTs[(tj + 8 + e) * 72 + ty] = q1[e];
    }
    __syncthreads();                     // (2) VTs ready

    f32x4 acc[4];
    {
      f32x4 z = {0.f, 0.f, 0.f, 0.f};
#pragma unroll
      for (int i = 0; i < 4; i++) acc[i] = z;
    }
#pragma unroll
    for (int ks = 0; ks < 2; ks++) {
      s16x8 qh = *(const s16x8*)(Th + (w * 16 + fl) * 72 + ks * 32 + fh * 8);
#pragma unroll
      for (int i = 0; i < 4; i++) {
        s16x8 p = *(const s16x8*)(VTs + (i * 16 + fl) * 72 + ks * 32 + fh * 8);
        acc[i] = __builtin_amdgcn_mfma_f32_16x16x32_bf16(p, qh, acc[i], 0, 0, 0);
      }
      s16x8 qw = *(const s16x8*)(Vs + (w * 16 + fl) * 72 + ks * 32 + fh * 8);
#pragma unroll
      for (int i = 0; i < 4; i++) {
        s16x8 p = *(const s16x8*)(Tw + (i * 16 + fl) * 72 + ks * 32 + fh * 8);
        acc[i] = __builtin_amdgcn_mfma_f32_16x16x32_bf16(p, qw, acc[i], 0, 0, 0);
      }
    }
    __syncthreads();                     // (3) all VTs reads done; epi writable

    {
      int y = w * 16 + fl;
#pragma unroll
      for (int i = 0; i < 4; i++) {
        u16x4 uq = *(const u16x4*)(Us + y * 72 + i * 16 + fh * 4);
        u16x4 pk;
#pragma unroll
        for (int e = 0; e < 4; e++) pk[e] = f2bf(acc[i][e] * bf2f(uq[e]));
        *(u16x4*)(epi + y * 72 + i * 16 + fh * 4) = pk;
      }
    }
    __syncthreads();                     // (4) epi complete

    {
      u16x8 a0 = *(const u16x8*)(epi + sy * 72 + sx);
      u16x8 a1 = *(const u16x8*)(epi + sy * 72 + sx + 8);
      u16* dst = gT + (size_t)c * M_TOT + b * 4096 + sy * 64 + sx;
      *(u16x8*)dst = a0;
      *(u16x8*)(dst + 8) = a1;
    }
    // no loop-end sync: next publish touches Vs/Us only (all reads finished
    // at (3)); next VT-build is fenced by next iteration's (1).
  }
}

// ---------------------------------------------------------------------------
extern "C" void kernel_launch(void* const* d_in, const int* in_sizes, int n_in,
                              void* d_out, int out_size, void* d_ws, size_t ws_size,
                              hipStream_t stream) {
  const float* x    = (const float*)d_in[0];
  const float* Wu   = (const float*)d_in[3];
  const float* bu   = (const float*)d_in[4];
  const float* Wv   = (const float*)d_in[5];
  const float* bv   = (const float*)d_in[6];
  const float* Wo   = (const float*)d_in[7];
  const float* bo   = (const float*)d_in[8];
  const float* r1pw = (const float*)d_in[9];
  const float* r1pb = (const float*)d_in[10];
  const float* r1lw = (const float*)d_in[11];
  const float* r1lb = (const float*)d_in[12];
  const float* r1ow = (const float*)d_in[13];
  const float* r1ob = (const float*)d_in[14];
  const float* r2pw = (const float*)d_in[15];
  const float* r2pb = (const float*)d_in[16];
  const float* r2lw = (const float*)d_in[17];
  const float* r2lb = (const float*)d_in[18];
  const float* r2ow = (const float*)d_in[19];
  const float* r2ob = (const float*)d_in[20];
  float* outp = (float*)d_out;

  char* ws = (char*)d_ws;
  size_t off = 0;
  auto carve = [&](size_t bytes) {
    char* p = ws + off;
    off += (bytes + 255) & ~(size_t)255;
    return p;
  };
  u16*   xn   = (u16*)carve((size_t)M_TOT * 384 * 2);
  u16*   uT   = (u16*)carve((size_t)768 * M_TOT * 2);
  u16*   vT   = (u16*)carve((size_t)768 * M_TOT * 2);
  u16*   gT   = (u16*)carve((size_t)768 * M_TOT * 2);
  u16*   Wuvt = (u16*)carve((size_t)1536 * 384 * 2);
  u16*   Wot  = (u16*)carve((size_t)384 * 768 * 2);
  float* awT  = (float*)carve((size_t)768 * 128 * 4);
  float* ahT  = (float*)carve((size_t)768 * 128 * 4);

  // RPE scratch aliased into gT region (gT written only later, by conv_k)
  char* rb  = (char*)gT;
  u16*   lwT = (u16*)rb;                               // 3 MB
  u16*   owT = (u16*)(rb + 3145728);                   // 1.5 MB
  float* X0  = (float*)(rb + 3145728 + 1572864);
  float* X1  = X0 + 256 * 512;

  setup_k<<<11488, 256, 0, stream>>>(x, xn, Wu, Wv, Wo, Wuvt, Wot,
                                     r1lw, r1ow, r2lw, r2ow, lwT, owT,
                                     r1pw, r1pb, r2pw, r2pb, X0);

  rpe_layer_k<512, false><<<16, 256, 0, stream>>>(X0, lwT, lwT + 3 * 262144,
                                                  r1lb, r2lb, X1, X1 + 128 * 512);
  rpe_layer_k<512, false><<<16, 256, 0, stream>>>(X1, lwT + 262144, lwT + 4 * 262144,
                                                  r1lb + 512, r2lb + 512, X0, X0 + 128 * 512);
  rpe_layer_k<512, false><<<16, 256, 0, stream>>>(X0, lwT + 2 * 262144, lwT + 5 * 262144,
                                                  r1lb + 1024, r2lb + 1024, X1, X1 + 128 * 512);
  rpe_layer_k<768, true><<<24, 256, 0, stream>>>(X1, owT, owT + 393216,
                                                 r1ob, r2ob, awT, ahT);

  // u|v GEMM: M=32768, N=1536, K=384 -> uT, vT (both (C,M))
  gemm0_k<<<256 * 6, 512, 0, stream>>>(xn, Wuvt, uT, vT, bu, bv);
  // conv + gate -> gT (C,M); block = channel
  conv_k<<<768, 256, 0, stream>>>(vT, uT, ahT, awT, gT);
  // out GEMM: M=32768, N=384(full), K=768 (+bo +x residual)
  gemm2_k<<<256, 512, 0, stream>>>(gT, Wot, outp, bo, x);
}